// Round 7
// baseline (1996.302 us; speedup 1.0000x reference)
//
#include <hip/hip_runtime.h>
#include <math.h>

#define N_PROP 256
#define NUM_CLASS 80
#define H_FEAT 50
#define W_FEAT 80
#define K_DIM 200704        // 1024*14*14
#define D_HID 1024
#define SPATIAL_SCALE 0.0625f
#define SCALE_CLAMP 4.135166556742356f   // log(1000/16)
#define IMG_W_F 1280.0f
#define IMG_H_F 800.0f

// ---------------- RoIAlign: A[m][k], k = c*196 + ph*14 + pw ----------------
__global__ void roi_kernel(const float* __restrict__ F, const float* __restrict__ props,
                           float* __restrict__ A) {
  const int tid = threadIdx.x;
  const int m = blockIdx.y;
  const int cg = blockIdx.x;                 // channel group of 128
  __shared__ float w00[196], w01[196], w10[196], w11[196];
  __shared__ int o00[196], o01[196], o10[196], o11[196];
  const float x1s = props[m*4+0]*SPATIAL_SCALE;
  const float y1s = props[m*4+1]*SPATIAL_SCALE;
  const float x2s = props[m*4+2]*SPATIAL_SCALE;
  const float y2s = props[m*4+3]*SPATIAL_SCALE;
  const float bwf = fmaxf(x2s-x1s, 1.0f) / 14.0f;
  const float bhf = fmaxf(y2s-y1s, 1.0f) / 14.0f;
  if (tid < 196) {
    int ph = tid / 14, pw = tid - ph*14;
    float X = x1s + (pw + 0.5f)*bwf;
    float Y = y1s + (ph + 0.5f)*bhf;
    bool valid = (Y >= -1.0f) && (Y <= (float)H_FEAT) && (X >= -1.0f) && (X <= (float)W_FEAT);
    float x = fminf(fmaxf(X, 0.0f), (float)(W_FEAT-1));
    float y = fminf(fmaxf(Y, 0.0f), (float)(H_FEAT-1));
    float xf = floorf(x), yf = floorf(y);
    int ix0 = (int)xf, iy0 = (int)yf;
    int ix1 = min(ix0+1, W_FEAT-1), iy1 = min(iy0+1, H_FEAT-1);
    float lx = x-xf, ly = y-yf, hx = 1.0f-lx, hy = 1.0f-ly;
    float v = valid ? 1.0f : 0.0f;
    w00[tid] = hy*hx*v; w01[tid] = hy*lx*v; w10[tid] = ly*hx*v; w11[tid] = ly*lx*v;
    o00[tid] = iy0*W_FEAT+ix0; o01[tid] = iy0*W_FEAT+ix1;
    o10[tid] = iy1*W_FEAT+ix0; o11[tid] = iy1*W_FEAT+ix1;
  }
  __syncthreads();
  const int base_c = cg*128;
  float* Arow = A + (size_t)m*K_DIM + (size_t)base_c*196;
  for (int it = 0; it < 98; ++it) {          // 128*196/256
    int idx = it*256 + tid;
    int c = idx / 196;
    int b = idx - c*196;
    const float* f = F + (size_t)(base_c + c)*4000;
    float val = w00[b]*f[o00[b]] + w01[b]*f[o01[b]] + w10[b]*f[o10[b]] + w11[b]*f[o11[b]];
    Arow[idx] = val;
  }
}

// ---------------- FC GEMM fp32, split-K partials ----------------
#define BM 64
#define BN 64
#define BK 32
#define KSPLIT 16
#define KCHUNK (K_DIM / KSPLIT)   // 12544
#define KSTEPS (KCHUNK / BK)      // 392

__global__ __launch_bounds__(256) void gemm_kernel(const float* __restrict__ A,
                                                   const float* __restrict__ B,
                                                   float* __restrict__ P) {
  __shared__ __align__(16) float As[BK][BM+4];
  __shared__ __align__(16) float Bs[BK][BN];
  const int tid = threadIdx.x;
  const int tx = tid & 15, ty = tid >> 4;
  const int bn = blockIdx.x * BN;
  const int bm = blockIdx.y * BM;
  const int k0 = blockIdx.z * KCHUNK;
  float acc[4][4] = {};
  const int ar = tid >> 3;          // 0..31
  const int ac = (tid & 7) * 4;     // 0,4,..,28
  const int br = tid >> 4;          // 0..15
  const int bc = (tid & 15) * 4;
  for (int step = 0; step < KSTEPS; ++step) {
    const int kb = k0 + step*BK;
    #pragma unroll
    for (int p = 0; p < 2; ++p) {   // A tile 64x32 -> transposed into LDS
      int r = ar + p*32;
      float4 v = *(const float4*)(A + (size_t)(bm + r)*K_DIM + kb + ac);
      As[ac+0][r] = v.x; As[ac+1][r] = v.y; As[ac+2][r] = v.z; As[ac+3][r] = v.w;
    }
    #pragma unroll
    for (int p = 0; p < 2; ++p) {   // B tile 32x64
      int r = br + p*16;
      *(float4*)&Bs[r][bc] = *(const float4*)(B + (size_t)(kb + r)*D_HID + bn + bc);
    }
    __syncthreads();
    #pragma unroll
    for (int kk = 0; kk < BK; ++kk) {
      float4 a = *(const float4*)&As[kk][ty*4];
      float4 b = *(const float4*)&Bs[kk][tx*4];
      float av[4] = {a.x,a.y,a.z,a.w};
      float bv[4] = {b.x,b.y,b.z,b.w};
      #pragma unroll
      for (int i = 0; i < 4; ++i)
        #pragma unroll
        for (int j = 0; j < 4; ++j)
          acc[i][j] = fmaf(av[i], bv[j], acc[i][j]);
    }
    __syncthreads();
  }
  float* Pp = P + (size_t)blockIdx.z * (N_PROP*D_HID);
  #pragma unroll
  for (int i = 0; i < 4; ++i) {
    float4 v = make_float4(acc[i][0], acc[i][1], acc[i][2], acc[i][3]);
    *(float4*)(Pp + (size_t)(bm + ty*4 + i)*D_HID + bn + tx*4) = v;
  }
}

__global__ void reduce_kernel(const float* __restrict__ P, float* __restrict__ X) {
  int i = blockIdx.x*256 + threadIdx.x;
  float s = 0.0f;
  #pragma unroll
  for (int r = 0; r < KSPLIT; ++r) s += P[(size_t)r*(N_PROP*D_HID) + i];
  X[i] = s;
}

// ---------------- heads + softmax + ORDER KEY ----------------
// key[m] = log(rest) of the argmax class = (m2 - mx) + log(sum_{j!=amax} exp(lg_j - m2)).
// Ordering by key asc == ordering by true softmax score desc at logit resolution,
// which matches the high-precision reference even where f32 scores saturate to 1.0.
__global__ void heads_kernel(const float* __restrict__ X, const float* __restrict__ bfc,
                             const float* __restrict__ wcls, const float* __restrict__ bcls,
                             const float* __restrict__ wbox, const float* __restrict__ bbox,
                             float* __restrict__ scores, float* __restrict__ deltas,
                             float* __restrict__ keym) {
  const int tid = threadIdx.x, m = blockIdx.x;
  __shared__ float xs[1024];
  __shared__ float lg[81];
  __shared__ float red[2];
  #pragma unroll
  for (int r = 0; r < 4; ++r) {
    int k = r*256 + tid;
    xs[k] = X[m*1024 + k] + bfc[k];
  }
  __syncthreads();
  for (int j = tid; j < 401; j += 256) {
    if (j < 81) {
      const float* w = wcls + j;
      float accv = bcls[j];
      #pragma unroll 8
      for (int k = 0; k < 1024; ++k) accv = fmaf(xs[k], w[(size_t)k*81], accv);
      lg[j] = accv;
    } else {
      int jb = j - 81;
      const float* w = wbox + jb;
      float accv = bbox[jb];
      #pragma unroll 8
      for (int k = 0; k < 1024; ++k) accv = fmaf(xs[k], w[(size_t)k*320], accv);
      deltas[m*320 + jb] = accv;
    }
  }
  __syncthreads();
  if (tid == 0) {
    float mx = lg[0]; int amax = 0;
    for (int j = 1; j < 81; ++j) if (lg[j] > mx) { mx = lg[j]; amax = j; }
    float sm = 0.0f;
    for (int j = 0; j < 81; ++j) sm += expf(lg[j]-mx);
    float m2 = -1e30f;
    for (int j = 0; j < 81; ++j) if (j != amax) m2 = fmaxf(m2, lg[j]);
    float s2 = 0.0f;
    for (int j = 0; j < 81; ++j) if (j != amax) s2 += expf(lg[j]-m2);
    keym[m] = (m2 - mx) + logf(s2);   // log(rest) of argmax class, stable
    red[0] = mx; red[1] = sm;
  }
  __syncthreads();
  if (tid < 80) scores[m*80 + tid] = expf(lg[tid+1]-red[0]) / red[1];
}

// ---------------- selection + NMS + f32 output ----------------
// sort candidates by (key asc == true-score desc, flat idx asc)
__global__ void detect_kernel(const float* __restrict__ scores, const float* __restrict__ deltas,
                              const float* __restrict__ props, const float* __restrict__ keym,
                              float* __restrict__ out) {
  const int tid = threadIdx.x;
  __shared__ int s_cnt;
  __shared__ float g_key[256];
  __shared__ float g_score[256];
  __shared__ int   g_idx[256];
  __shared__ float c_score[256];
  __shared__ int   c_idx[256];
  __shared__ float bxs[256][4];
  __shared__ int   bcls[256];
  __shared__ unsigned long long supp[256][4];
  if (tid == 0) s_cnt = 0;
  g_key[tid] = 1e30f; g_score[tid] = -1.0f; g_idx[tid] = 0x7FFFFFFF;
  c_score[tid] = -1.0f; c_idx[tid] = 0x7FFFFFFF;
  bxs[tid][0] = bxs[tid][1] = bxs[tid][2] = bxs[tid][3] = 0.0f;
  bcls[tid] = 0;
  __syncthreads();
  for (int t = 0; t < 80; ++t) {
    int i = t*256 + tid;
    float s = scores[i];
    if (s > 0.5f) {
      int p = atomicAdd(&s_cnt, 1);
      if (p < 256) { g_score[p] = s; g_idx[p] = i; g_key[p] = keym[i/80]; }
    }
  }
  __syncthreads();
  const int C = min(s_cnt, 256);
  // exact rank sort by (key asc, idx asc); ranks unique
  if (tid < C) {
    float kt = g_key[tid]; int si = g_idx[tid]; float st = g_score[tid];
    int rank = 0;
    for (int u = 0; u < C; ++u) {
      float ku = g_key[u]; int iu = g_idx[u];
      if ((ku < kt) || (ku == kt && iu < si)) ++rank;
    }
    c_score[rank] = st; c_idx[rank] = si;
  }
  __syncthreads();
  if (tid < C) {
    int fi = c_idx[tid];
    int m = fi / 80, j = fi - m*80;
    float px1 = props[m*4+0], py1 = props[m*4+1], px2 = props[m*4+2], py2 = props[m*4+3];
    float w = px2-px1, h = py2-py1;
    float cx = px1 + 0.5f*w, cy = py1 + 0.5f*h;
    const float* d = deltas + m*320 + j*4;
    float dx = d[0]/10.0f, dy = d[1]/10.0f;
    float dw = fminf(d[2]/5.0f, SCALE_CLAMP), dh = fminf(d[3]/5.0f, SCALE_CLAMP);
    float pcx = dx*w + cx, pcy = dy*h + cy;
    float pw = expf(dw)*w, ph = expf(dh)*h;
    bxs[tid][0] = fminf(fmaxf(pcx - 0.5f*pw, 0.0f), IMG_W_F);
    bxs[tid][1] = fminf(fmaxf(pcy - 0.5f*ph, 0.0f), IMG_H_F);
    bxs[tid][2] = fminf(fmaxf(pcx + 0.5f*pw, 0.0f), IMG_W_F);
    bxs[tid][3] = fminf(fmaxf(pcy + 0.5f*ph, 0.0f), IMG_H_F);
    bcls[tid] = j;
  }
  __syncthreads();
  unsigned long long row[4] = {0,0,0,0};
  if (tid < C) {
    float ax1=bxs[tid][0], ay1=bxs[tid][1], ax2=bxs[tid][2], ay2=bxs[tid][3];
    float aarea = fmaxf(ax2-ax1,0.f)*fmaxf(ay2-ay1,0.f);
    int acl = bcls[tid];
    for (int j2 = tid+1; j2 < C; ++j2) {
      if (bcls[j2] != acl) continue;   // class-offset boxes: cross-class IoU == 0
      float b1=bxs[j2][0], b2=bxs[j2][1], b3=bxs[j2][2], b4=bxs[j2][3];
      float barea = fmaxf(b3-b1,0.f)*fmaxf(b4-b2,0.f);
      float iw = fmaxf(fminf(ax2,b3) - fmaxf(ax1,b1), 0.f);
      float ih = fmaxf(fminf(ay2,b4) - fmaxf(ay1,b2), 0.f);
      float inter = iw*ih;
      float iou = inter / fmaxf(aarea + barea - inter, 1e-9f);
      if (iou > 0.7f) row[j2>>6] |= (1ull << (j2 & 63));
    }
  }
  supp[tid][0]=row[0]; supp[tid][1]=row[1]; supp[tid][2]=row[2]; supp[tid][3]=row[3];
  __syncthreads();
  // defaults: boxes 0 [0,800), scores 0 [800,1000), classes -1 [1000,1200)
  for (int i = tid; i < 1200; i += 256) out[i] = (i >= 1000) ? -1.0f : 0.0f;
  __syncthreads();
  if (tid == 0) {
    unsigned long long rem[4] = {0,0,0,0};
    int oc = 0;
    for (int i = 0; i < C; ++i) {
      if ((rem[i>>6] >> (i & 63)) & 1ull) continue;
      if (oc < 200) {
        out[oc*4+0]=bxs[i][0]; out[oc*4+1]=bxs[i][1]; out[oc*4+2]=bxs[i][2]; out[oc*4+3]=bxs[i][3];
        out[800+oc]  = c_score[i];
        out[1000+oc] = (float)bcls[i];
      }
      ++oc;
      rem[0]|=supp[i][0]; rem[1]|=supp[i][1]; rem[2]|=supp[i][2]; rem[3]|=supp[i][3];
    }
  }
}

extern "C" void kernel_launch(void* const* d_in, const int* in_sizes, int n_in,
                              void* d_out, int out_size, void* d_ws, size_t ws_size,
                              hipStream_t stream) {
  const float* F     = (const float*)d_in[0];
  const float* props = (const float*)d_in[1];
  const float* wfc   = (const float*)d_in[2];
  const float* bfc   = (const float*)d_in[3];
  const float* wcls  = (const float*)d_in[4];
  const float* bcls  = (const float*)d_in[5];
  const float* wbox  = (const float*)d_in[6];
  const float* bbox  = (const float*)d_in[7];
  float* out = (float*)d_out;
  float* ws  = (float*)d_ws;

  float* A  = ws;                                    // 256*200704
  float* P  = A + (size_t)N_PROP*K_DIM;              // 16*256*1024
  float* X  = P + (size_t)KSPLIT*N_PROP*D_HID;       // 256*1024
  float* SC = X + (size_t)N_PROP*D_HID;              // 256*80
  float* DL = SC + (size_t)N_PROP*NUM_CLASS;         // 256*320
  float* KM = DL + (size_t)N_PROP*NUM_CLASS*4;       // 256
  size_t need = ((size_t)N_PROP*K_DIM + (size_t)KSPLIT*N_PROP*D_HID +
                 (size_t)N_PROP*D_HID + (size_t)N_PROP*NUM_CLASS +
                 (size_t)N_PROP*NUM_CLASS*4 + N_PROP) * sizeof(float);
  if (ws_size < need) {
    hipMemsetAsync(d_out, 0x7F, (size_t)out_size*sizeof(float), stream);
    return;
  }

  roi_kernel   <<<dim3(8, N_PROP),      256, 0, stream>>>(F, props, A);
  gemm_kernel  <<<dim3(16, 4, KSPLIT),  256, 0, stream>>>(A, wfc, P);
  reduce_kernel<<<(N_PROP*D_HID)/256,   256, 0, stream>>>(P, X);
  heads_kernel <<<N_PROP,               256, 0, stream>>>(X, bfc, wcls, bcls, wbox, bbox, SC, DL, KM);
  detect_kernel<<<1,                    256, 0, stream>>>(SC, DL, props, KM, out);
}

// Round 8
// 1126.478 us; speedup vs baseline: 1.7722x; 1.7722x over previous
//
#include <hip/hip_runtime.h>
#include <math.h>

#define N_PROP 256
#define NUM_CLASS 80
#define H_FEAT 50
#define W_FEAT 80
#define K_DIM 200704        // 1024*14*14
#define D_HID 1024
#define SPATIAL_SCALE 0.0625f
#define SCALE_CLAMP 4.135166556742356f   // log(1000/16)
#define IMG_W_F 1280.0f
#define IMG_H_F 800.0f

typedef unsigned short ushort_t;
typedef __attribute__((ext_vector_type(8))) short short8v;       // 8 bf16 = 4 VGPR
typedef __attribute__((ext_vector_type(16))) float f32x16;       // 32x32 acc
typedef __attribute__((ext_vector_type(4))) unsigned short ushort4v;

__device__ __forceinline__ unsigned short f2bf(float f) {
  unsigned int u = __builtin_bit_cast(unsigned int, f);
  u += 0x7FFFu + ((u >> 16) & 1u);                 // RNE
  return (unsigned short)(u >> 16);
}
__device__ __forceinline__ float bf2f(unsigned short h) {
  unsigned int u = ((unsigned int)h) << 16;
  return __builtin_bit_cast(float, u);
}

// ---------------- RoIAlign -> A as bf16 hi/lo pairs, k = c*196 + ph*14 + pw ----------------
__global__ void roi_kernel(const float* __restrict__ F, const float* __restrict__ props,
                           ushort_t* __restrict__ Ahi, ushort_t* __restrict__ Alo) {
  const int tid = threadIdx.x;
  const int m = blockIdx.y;
  const int cg = blockIdx.x;                 // channel group of 128
  __shared__ float w00[196], w01[196], w10[196], w11[196];
  __shared__ int o00[196], o01[196], o10[196], o11[196];
  const float x1s = props[m*4+0]*SPATIAL_SCALE;
  const float y1s = props[m*4+1]*SPATIAL_SCALE;
  const float x2s = props[m*4+2]*SPATIAL_SCALE;
  const float y2s = props[m*4+3]*SPATIAL_SCALE;
  const float bwf = fmaxf(x2s-x1s, 1.0f) / 14.0f;
  const float bhf = fmaxf(y2s-y1s, 1.0f) / 14.0f;
  if (tid < 196) {
    int ph = tid / 14, pw = tid - ph*14;
    float X = x1s + (pw + 0.5f)*bwf;
    float Y = y1s + (ph + 0.5f)*bhf;
    bool valid = (Y >= -1.0f) && (Y <= (float)H_FEAT) && (X >= -1.0f) && (X <= (float)W_FEAT);
    float x = fminf(fmaxf(X, 0.0f), (float)(W_FEAT-1));
    float y = fminf(fmaxf(Y, 0.0f), (float)(H_FEAT-1));
    float xf = floorf(x), yf = floorf(y);
    int ix0 = (int)xf, iy0 = (int)yf;
    int ix1 = min(ix0+1, W_FEAT-1), iy1 = min(iy0+1, H_FEAT-1);
    float lx = x-xf, ly = y-yf, hx = 1.0f-lx, hy = 1.0f-ly;
    float v = valid ? 1.0f : 0.0f;
    w00[tid] = hy*hx*v; w01[tid] = hy*lx*v; w10[tid] = ly*hx*v; w11[tid] = ly*lx*v;
    o00[tid] = iy0*W_FEAT+ix0; o01[tid] = iy0*W_FEAT+ix1;
    o10[tid] = iy1*W_FEAT+ix0; o11[tid] = iy1*W_FEAT+ix1;
  }
  __syncthreads();
  const int base_c = cg*128;
  const size_t rowbase = (size_t)m*K_DIM + (size_t)base_c*196;
  for (int it = 0; it < 98; ++it) {          // 128*196/256
    int idx = it*256 + tid;
    int c = idx / 196;
    int b = idx - c*196;
    const float* f = F + (size_t)(base_c + c)*4000;
    float val = w00[b]*f[o00[b]] + w01[b]*f[o01[b]] + w10[b]*f[o10[b]] + w11[b]*f[o11[b]];
    unsigned short h = f2bf(val);
    unsigned short l = f2bf(val - bf2f(h));
    Ahi[rowbase + idx] = h;
    Alo[rowbase + idx] = l;
  }
}

// ---------------- split-bf16 MFMA GEMM: X = A @ W, K split across z ----------------
// BM=256 (all M), BN=128, BK=32. A via global_load_lds; B (f32 [k][n]) reg-staged,
// converted to bf16 hi/lo, transpose-scattered into LDS with XOR swizzle.
// LDS ushort layout:
//   A: plane(2)*8192 + kb(4)*2048 + row(256)*8      (32 KB)
//   B: 16384 + plane(2)*4096 + kb(4)*1024 + scol(128)*8   (16 KB), scol = col ^ ((col>>3)&7)
__global__ __launch_bounds__(256, 2) void mfma_gemm(
    const ushort_t* __restrict__ Ahi, const ushort_t* __restrict__ Alo,
    const float* __restrict__ B, float* __restrict__ P, int steps_per) {
  __shared__ ushort_t lds[24576];
  const int tid = threadIdx.x;
  const int wv = tid >> 6, lane = tid & 63, l31 = lane & 31, lhi = lane >> 5;
  const int bn = blockIdx.x * 128;
  const int z  = blockIdx.y;
  const int step0 = z * steps_per;
  int steps = steps_per;
  if (step0 + steps > 6272) steps = 6272 - step0;   // may be <= 0

  f32x16 acc[2][4];
  #pragma unroll
  for (int a = 0; a < 2; ++a)
    #pragma unroll
    for (int b = 0; b < 4; ++b)
      #pragma unroll
      for (int e = 0; e < 16; ++e) acc[a][b][e] = 0.0f;

  if (steps > 0) {
    const ushort_t* asrc[8];
    #pragma unroll
    for (int i = 0; i < 8; ++i) {
      int s = i*256 + tid;
      int plane = s >> 10, kb = (s >> 8) & 3, row = s & 255;
      const ushort_t* basep = plane ? Alo : Ahi;
      asrc[i] = basep + (size_t)row * K_DIM + step0*32 + kb*8;
    }
    const int p = tid >> 5, c4 = tid & 31;
    const float* bsrc = B + (size_t)(step0*32 + 4*p) * D_HID + bn + c4*4;

    for (int s = 0; s < steps; ++s) {
      // ---- stage A (global_load_lds, 8 x 4KB block-wide) ----
      #pragma unroll
      for (int i = 0; i < 8; ++i) {
        __builtin_amdgcn_global_load_lds(asrc[i], &lds[(i*256 + wv*64)*8], 16, 0, 0);
        asrc[i] += 32;
      }
      // ---- stage B: load f32, split to bf16 hi/lo, transposed+swizzled LDS write ----
      float4 bv0 = *(const float4*)(bsrc);
      float4 bv1 = *(const float4*)(bsrc + D_HID);
      float4 bv2 = *(const float4*)(bsrc + 2*D_HID);
      float4 bv3 = *(const float4*)(bsrc + 3*D_HID);
      bsrc += 32 * D_HID;
      {
        ushort4v hv, lv; int col, scol; unsigned idx;
        #define DO_COL(c, g0,g1,g2,g3) \
          hv[0]=f2bf(g0); lv[0]=f2bf((g0)-bf2f(hv[0])); \
          hv[1]=f2bf(g1); lv[1]=f2bf((g1)-bf2f(hv[1])); \
          hv[2]=f2bf(g2); lv[2]=f2bf((g2)-bf2f(hv[2])); \
          hv[3]=f2bf(g3); lv[3]=f2bf((g3)-bf2f(hv[3])); \
          col = c4*4 + (c); scol = col ^ ((col>>3)&7); \
          idx = 16384u + (unsigned)((p>>1)*1024 + scol*8 + 4*(p&1)); \
          *(ushort4v*)&lds[idx] = hv; *(ushort4v*)&lds[idx + 4096] = lv;
        DO_COL(0, bv0.x, bv1.x, bv2.x, bv3.x)
        DO_COL(1, bv0.y, bv1.y, bv2.y, bv3.y)
        DO_COL(2, bv0.z, bv1.z, bv2.z, bv3.z)
        DO_COL(3, bv0.w, bv1.w, bv2.w, bv3.w)
        #undef DO_COL
      }
      __syncthreads();   // drains glds (vmcnt0) + ds_writes
      // ---- compute: 2 x (12 ds_read_b128 + 24 MFMA) ----
      #pragma unroll
      for (int kk = 0; kk < 2; ++kk) {
        short8v ah[2], al[2], bh[4], bl[4];
        #pragma unroll
        for (int ms = 0; ms < 2; ++ms) {
          unsigned ai = (unsigned)((kk*2 + lhi)*2048 + (wv*64 + ms*32 + l31)*8);
          ah[ms] = *(const short8v*)&lds[ai];
          al[ms] = *(const short8v*)&lds[ai + 8192];
        }
        #pragma unroll
        for (int ns = 0; ns < 4; ++ns) {
          int col = ns*32 + l31, scol = col ^ ((col>>3)&7);
          unsigned bi = 16384u + (unsigned)((kk*2 + lhi)*1024 + scol*8);
          bh[ns] = *(const short8v*)&lds[bi];
          bl[ns] = *(const short8v*)&lds[bi + 4096];
        }
        #pragma unroll
        for (int ms = 0; ms < 2; ++ms)
          #pragma unroll
          for (int ns = 0; ns < 4; ++ns) {
            acc[ms][ns] = __builtin_amdgcn_mfma_f32_32x32x16_bf16(ah[ms], bh[ns], acc[ms][ns], 0, 0, 0);
            acc[ms][ns] = __builtin_amdgcn_mfma_f32_32x32x16_bf16(ah[ms], bl[ns], acc[ms][ns], 0, 0, 0);
            acc[ms][ns] = __builtin_amdgcn_mfma_f32_32x32x16_bf16(al[ms], bh[ns], acc[ms][ns], 0, 0, 0);
          }
      }
      __syncthreads();
    }
  }
  // write partial tile: D layout col=lane&31, row=(r&3)+8*(r>>2)+4*(lane>>5)
  float* Pp = P + (size_t)z * (N_PROP * D_HID);
  #pragma unroll
  for (int ms = 0; ms < 2; ++ms)
    #pragma unroll
    for (int ns = 0; ns < 4; ++ns)
      #pragma unroll
      for (int r = 0; r < 16; ++r) {
        int row = wv*64 + ms*32 + (r & 3) + 8*(r >> 2) + 4*lhi;
        int col = bn + ns*32 + l31;
        Pp[(size_t)row * D_HID + col] = acc[ms][ns][r];
      }
}

__global__ void reduce_kernel(const float* __restrict__ P, float* __restrict__ X, int ksplit) {
  int i = blockIdx.x*256 + threadIdx.x;
  float s = 0.0f;
  for (int r = 0; r < ksplit; ++r) s += P[(size_t)r*(N_PROP*D_HID) + i];
  X[i] = s;
}

// ---------------- heads + softmax + ORDER KEY (log-rest, saturation-proof) ----------------
__global__ void heads_kernel(const float* __restrict__ X, const float* __restrict__ bfc,
                             const float* __restrict__ wcls, const float* __restrict__ bcls,
                             const float* __restrict__ wbox, const float* __restrict__ bbox,
                             float* __restrict__ scores, float* __restrict__ deltas,
                             float* __restrict__ keym) {
  const int tid = threadIdx.x, m = blockIdx.x;
  __shared__ float xs[1024];
  __shared__ float lg[81];
  __shared__ float red[2];
  #pragma unroll
  for (int r = 0; r < 4; ++r) {
    int k = r*256 + tid;
    xs[k] = X[m*1024 + k] + bfc[k];
  }
  __syncthreads();
  for (int j = tid; j < 401; j += 256) {
    if (j < 81) {
      const float* w = wcls + j;
      float accv = bcls[j];
      #pragma unroll 8
      for (int k = 0; k < 1024; ++k) accv = fmaf(xs[k], w[(size_t)k*81], accv);
      lg[j] = accv;
    } else {
      int jb = j - 81;
      const float* w = wbox + jb;
      float accv = bbox[jb];
      #pragma unroll 8
      for (int k = 0; k < 1024; ++k) accv = fmaf(xs[k], w[(size_t)k*320], accv);
      deltas[m*320 + jb] = accv;
    }
  }
  __syncthreads();
  if (tid == 0) {
    float mx = lg[0]; int amax = 0;
    for (int j = 1; j < 81; ++j) if (lg[j] > mx) { mx = lg[j]; amax = j; }
    float sm = 0.0f;
    for (int j = 0; j < 81; ++j) sm += expf(lg[j]-mx);
    float m2 = -1e30f;
    for (int j = 0; j < 81; ++j) if (j != amax) m2 = fmaxf(m2, lg[j]);
    float s2 = 0.0f;
    for (int j = 0; j < 81; ++j) if (j != amax) s2 += expf(lg[j]-m2);
    keym[m] = (m2 - mx) + logf(s2);
    red[0] = mx; red[1] = sm;
  }
  __syncthreads();
  if (tid < 80) scores[m*80 + tid] = expf(lg[tid+1]-red[0]) / red[1];
}

// ---------------- selection + NMS + f32 output ----------------
__global__ void detect_kernel(const float* __restrict__ scores, const float* __restrict__ deltas,
                              const float* __restrict__ props, const float* __restrict__ keym,
                              float* __restrict__ out) {
  const int tid = threadIdx.x;
  __shared__ int s_cnt;
  __shared__ float g_key[256];
  __shared__ float g_score[256];
  __shared__ int   g_idx[256];
  __shared__ float c_score[256];
  __shared__ int   c_idx[256];
  __shared__ float bxs[256][4];
  __shared__ int   bcls[256];
  __shared__ unsigned long long supp[256][4];
  if (tid == 0) s_cnt = 0;
  g_key[tid] = 1e30f; g_score[tid] = -1.0f; g_idx[tid] = 0x7FFFFFFF;
  c_score[tid] = -1.0f; c_idx[tid] = 0x7FFFFFFF;
  bxs[tid][0] = bxs[tid][1] = bxs[tid][2] = bxs[tid][3] = 0.0f;
  bcls[tid] = 0;
  __syncthreads();
  for (int t = 0; t < 80; ++t) {
    int i = t*256 + tid;
    float s = scores[i];
    if (s > 0.5f) {
      int p = atomicAdd(&s_cnt, 1);
      if (p < 256) { g_score[p] = s; g_idx[p] = i; g_key[p] = keym[i/80]; }
    }
  }
  __syncthreads();
  const int C = min(s_cnt, 256);
  if (tid < C) {
    float kt = g_key[tid]; int si = g_idx[tid]; float st = g_score[tid];
    int rank = 0;
    for (int u = 0; u < C; ++u) {
      float ku = g_key[u]; int iu = g_idx[u];
      if ((ku < kt) || (ku == kt && iu < si)) ++rank;
    }
    c_score[rank] = st; c_idx[rank] = si;
  }
  __syncthreads();
  if (tid < C) {
    int fi = c_idx[tid];
    int m = fi / 80, j = fi - m*80;
    float px1 = props[m*4+0], py1 = props[m*4+1], px2 = props[m*4+2], py2 = props[m*4+3];
    float w = px2-px1, h = py2-py1;
    float cx = px1 + 0.5f*w, cy = py1 + 0.5f*h;
    const float* d = deltas + m*320 + j*4;
    float dx = d[0]/10.0f, dy = d[1]/10.0f;
    float dw = fminf(d[2]/5.0f, SCALE_CLAMP), dh = fminf(d[3]/5.0f, SCALE_CLAMP);
    float pcx = dx*w + cx, pcy = dy*h + cy;
    float pw = expf(dw)*w, ph = expf(dh)*h;
    bxs[tid][0] = fminf(fmaxf(pcx - 0.5f*pw, 0.0f), IMG_W_F);
    bxs[tid][1] = fminf(fmaxf(pcy - 0.5f*ph, 0.0f), IMG_H_F);
    bxs[tid][2] = fminf(fmaxf(pcx + 0.5f*pw, 0.0f), IMG_W_F);
    bxs[tid][3] = fminf(fmaxf(pcy + 0.5f*ph, 0.0f), IMG_H_F);
    bcls[tid] = j;
  }
  __syncthreads();
  unsigned long long row[4] = {0,0,0,0};
  if (tid < C) {
    float ax1=bxs[tid][0], ay1=bxs[tid][1], ax2=bxs[tid][2], ay2=bxs[tid][3];
    float aarea = fmaxf(ax2-ax1,0.f)*fmaxf(ay2-ay1,0.f);
    int acl = bcls[tid];
    for (int j2 = tid+1; j2 < C; ++j2) {
      if (bcls[j2] != acl) continue;
      float b1=bxs[j2][0], b2=bxs[j2][1], b3=bxs[j2][2], b4=bxs[j2][3];
      float barea = fmaxf(b3-b1,0.f)*fmaxf(b4-b2,0.f);
      float iw = fmaxf(fminf(ax2,b3) - fmaxf(ax1,b1), 0.f);
      float ih = fmaxf(fminf(ay2,b4) - fmaxf(ay1,b2), 0.f);
      float inter = iw*ih;
      float iou = inter / fmaxf(aarea + barea - inter, 1e-9f);
      if (iou > 0.7f) row[j2>>6] |= (1ull << (j2 & 63));
    }
  }
  supp[tid][0]=row[0]; supp[tid][1]=row[1]; supp[tid][2]=row[2]; supp[tid][3]=row[3];
  __syncthreads();
  for (int i = tid; i < 1200; i += 256) out[i] = (i >= 1000) ? -1.0f : 0.0f;
  __syncthreads();
  if (tid == 0) {
    unsigned long long rem[4] = {0,0,0,0};
    int oc = 0;
    for (int i = 0; i < C; ++i) {
      if ((rem[i>>6] >> (i & 63)) & 1ull) continue;
      if (oc < 200) {
        out[oc*4+0]=bxs[i][0]; out[oc*4+1]=bxs[i][1]; out[oc*4+2]=bxs[i][2]; out[oc*4+3]=bxs[i][3];
        out[800+oc]  = c_score[i];
        out[1000+oc] = (float)bcls[i];
      }
      ++oc;
      rem[0]|=supp[i][0]; rem[1]|=supp[i][1]; rem[2]|=supp[i][2]; rem[3]|=supp[i][3];
    }
  }
}

extern "C" void kernel_launch(void* const* d_in, const int* in_sizes, int n_in,
                              void* d_out, int out_size, void* d_ws, size_t ws_size,
                              hipStream_t stream) {
  const float* F     = (const float*)d_in[0];
  const float* props = (const float*)d_in[1];
  const float* wfc   = (const float*)d_in[2];
  const float* bfc   = (const float*)d_in[3];
  const float* wcls  = (const float*)d_in[4];
  const float* bcls  = (const float*)d_in[5];
  const float* wbox  = (const float*)d_in[6];
  const float* bbox  = (const float*)d_in[7];
  float* out = (float*)d_out;
  char* wsb  = (char*)d_ws;

  const size_t abytes = (size_t)N_PROP * K_DIM * 2;      // 102,760,448 per plane
  ushort_t* Ahi = (ushort_t*)wsb;
  ushort_t* Alo = (ushort_t*)(wsb + abytes);
  float* X  = (float*)(wsb + 2*abytes);                   // 262144
  float* SC = X + 262144;                                 // 20480
  float* DL = SC + 20480;                                 // 81920
  float* KM = DL + 81920;                                 // 256
  float* P  = KM + 256;                                   // ksplit * 1 MB
  const size_t fixed = 2*abytes + (size_t)(262144 + 20480 + 81920 + 256) * 4;
  if (ws_size < fixed + 2u*1048576u) {
    hipMemsetAsync(d_out, 0x7F, (size_t)out_size*sizeof(float), stream);
    return;
  }
  int ksplit = (int)((ws_size - fixed) / ((size_t)N_PROP * D_HID * 4));
  if (ksplit > 98) ksplit = 98;
  const int steps_per = (6272 + ksplit - 1) / ksplit;

  roi_kernel   <<<dim3(8, N_PROP),    256, 0, stream>>>(F, props, Ahi, Alo);
  mfma_gemm    <<<dim3(8, ksplit),    256, 0, stream>>>(Ahi, Alo, wfc, P, steps_per);
  reduce_kernel<<<1024,               256, 0, stream>>>(P, X, ksplit);
  heads_kernel <<<N_PROP,             256, 0, stream>>>(X, bfc, wcls, bcls, wbox, bbox, SC, DL, KM);
  detect_kernel<<<1,                  256, 0, stream>>>(SC, DL, props, KM, out);
}